// Round 2
// baseline (915.922 us; speedup 1.0000x reference)
//
#include <hip/hip_runtime.h>
#include <math.h>

#define N_NODES  100000
#define N_EDGES  3200000
#define K_IN     1433
#define NH       16
#define NO       7

#define TK       16
#define NC       ((K_IN + TK - 1) / TK)      // 90
#define LSTR     68                           // transposed-tile row stride (floats)
#define GR       64                           // rows per wave-tile
#define NTILE    ((N_NODES + GR - 1) / GR)    // 1563
#define GBLK     ((NTILE + 1) / 2)            // 782 blocks x 2 waves
#define NBLK_N   ((N_NODES + 255) / 256)      // 391 node-blocks for scans

typedef float f4  __attribute__((ext_vector_type(4)));
typedef float f4u __attribute__((ext_vector_type(4), aligned(4)));  // X rows are only 4B-aligned

// ---------------- K1: degree counts ----------------
__global__ void k_degrees(const int* __restrict__ src, const int* __restrict__ dst,
                          int* __restrict__ deg_out, int* __restrict__ deg_in) {
    int i = blockIdx.x * blockDim.x + threadIdx.x;
    int stride = gridDim.x * blockDim.x;
    for (; i < N_EDGES; i += stride) {
        atomicAdd(&deg_out[src[i]], 1);
        atomicAdd(&deg_in[dst[i]], 1);
    }
}

// ---------------- K2a: per-block sums of deg_in ----------------
__global__ void k_bsum(const int* __restrict__ deg_in, int* __restrict__ bsum) {
    int t = threadIdx.x;
    int i = blockIdx.x * 256 + t;
    int v = (i < N_NODES) ? deg_in[i] : 0;
#pragma unroll
    for (int o = 1; o < 64; o <<= 1) v += __shfl_xor(v, o);
    __shared__ int ws[4];
    if ((t & 63) == 0) ws[t >> 6] = v;
    __syncthreads();
    if (t == 0) bsum[blockIdx.x] = ws[0] + ws[1] + ws[2] + ws[3];
}

// ---------------- K2b: exclusive scan of block sums (1 block) ----------------
__global__ void k_scan(const int* __restrict__ bsum, int* __restrict__ boff) {
    __shared__ int s[512];
    int t = threadIdx.x;
    int my = (t < NBLK_N) ? bsum[t] : 0;
    s[t] = my;
    __syncthreads();
    for (int o = 1; o < 512; o <<= 1) {
        int v = (t >= o) ? s[t - o] : 0;
        __syncthreads();
        s[t] += v;
        __syncthreads();
    }
    if (t < NBLK_N) boff[t] = s[t] - my;   // exclusive
}

// ---------------- K2c: row_ptr + cursor ----------------
__global__ void k_rowptr(const int* __restrict__ deg_in, const int* __restrict__ boff,
                         int* __restrict__ row_ptr, int* __restrict__ cursor) {
    __shared__ int s[256];
    int t = threadIdx.x;
    int i = blockIdx.x * 256 + t;
    int my = (i < N_NODES) ? deg_in[i] : 0;
    s[t] = my;
    __syncthreads();
    for (int o = 1; o < 256; o <<= 1) {
        int v = (t >= o) ? s[t - o] : 0;
        __syncthreads();
        s[t] += v;
        __syncthreads();
    }
    if (i < N_NODES) {
        int e = boff[blockIdx.x] + s[t] - my;
        row_ptr[i] = e;
        cursor[i]  = e;
    }
}

// ---------------- K3: fill CSR adjacency (by dst) ----------------
__global__ void k_fill(const int* __restrict__ src, const int* __restrict__ dst,
                       int* __restrict__ cursor, int* __restrict__ adj) {
    int i = blockIdx.x * blockDim.x + threadIdx.x;
    int stride = gridDim.x * blockDim.x;
    for (; i < N_EDGES; i += stride) {
        int p = atomicAdd(&cursor[dst[i]], 1);
        adj[p] = src[i];
    }
}

// ---------------- K4: h = norm_src * (X @ W1) ----------------
// 64-row wave-tiles; 2 independent waves per block (no __syncthreads).
// LDS tile transposed [TK][LSTR]: reads conflict-free, writes 2-way (free).
__global__ __launch_bounds__(128)
void k_gemm1(const float* __restrict__ X, const float* __restrict__ W1,
             const int* __restrict__ deg_out, float* __restrict__ h) {
    __shared__ float sX[2][TK * LSTR];
    const int wid = threadIdx.x >> 6;
    const int t   = threadIdx.x & 63;
    const int tile = blockIdx.x * 2 + wid;
    const int row_base = tile * GR;
    if (row_base >= N_NODES) return;           // wave-uniform, no barriers used
    float* lds = sX[wid];
    const int q = t & 3;          // 16B granule within the 16-k chunk
    const int rsub = t >> 2;      // 0..15

    f4 acc0 = 0.f, acc1 = 0.f, acc2 = 0.f, acc3 = 0.f;
    f4 rv[4];

    // stage chunk 0 (k = 4q..4q+3, always < K_IN)
#pragma unroll
    for (int i = 0; i < 4; ++i) {
        int rg = row_base + i * 16 + rsub;
        rg = min(rg, N_NODES - 1);
        rv[i] = *(const f4u*)(X + (size_t)rg * K_IN + 4 * q);
    }

    for (int c = 0; c < NC; ++c) {
        // regs -> transposed LDS
        const int kcol = 4 * q;
#pragma unroll
        for (int i = 0; i < 4; ++i) {
            int r = i * 16 + rsub;
            lds[(kcol + 0) * LSTR + r] = rv[i][0];
            lds[(kcol + 1) * LSTR + r] = rv[i][1];
            lds[(kcol + 2) * LSTR + r] = rv[i][2];
            lds[(kcol + 3) * LSTR + r] = rv[i][3];
        }
        // issue next-chunk loads (in flight across compute)
        if (c + 1 < NC) {
            const int kn = (c + 1) * TK + 4 * q;
            if (kn + 3 < K_IN) {
#pragma unroll
                for (int i = 0; i < 4; ++i) {
                    int rg = row_base + i * 16 + rsub;
                    rg = min(rg, N_NODES - 1);
                    rv[i] = *(const f4u*)(X + (size_t)rg * K_IN + kn);
                }
            } else {
#pragma unroll
                for (int i = 0; i < 4; ++i) {
                    int rg = row_base + i * 16 + rsub;
                    rg = min(rg, N_NODES - 1);
                    const float* xr = X + (size_t)rg * K_IN;
#pragma unroll
                    for (int m = 0; m < 4; ++m)
                        rv[i][m] = (kn + m < K_IN) ? xr[kn + m] : 0.f;
                }
            }
        }
        __builtin_amdgcn_wave_barrier();   // keep LDS writes before reads
        const int k0 = c * TK;
#pragma unroll
        for (int kk = 0; kk < TK; ++kk) {
            float x = lds[kk * LSTR + t];
            int wk = min(k0 + kk, K_IN - 1);        // uniform; clamps tail (x==0 there)
            const float* wr = W1 + wk * NH;
            acc0 += x * *(const f4*)(wr + 0);
            acc1 += x * *(const f4*)(wr + 4);
            acc2 += x * *(const f4*)(wr + 8);
            acc3 += x * *(const f4*)(wr + 12);
        }
        __builtin_amdgcn_wave_barrier();   // keep next writes after reads
    }

    int rg = row_base + t;
    if (rg < N_NODES) {
        float ns = rsqrtf((float)max(deg_out[rg], 1));
        f4* hp = (f4*)(h + (size_t)rg * NH);
        hp[0] = acc0 * ns;
        hp[1] = acc1 * ns;
        hp[2] = acc2 * ns;
        hp[3] = acc3 * ns;
    }
}

// ---------------- K5: gather layer1 + relu + fused (.. @ W2) ----------------
// one wave per node; 4 lanes x float4 per edge -> 16 edges per wave-iteration
__global__ __launch_bounds__(256)
void k_layer1(const float* __restrict__ h, const int* __restrict__ adj,
              const int* __restrict__ row_ptr, const int* __restrict__ deg_in,
              const int* __restrict__ deg_out, const float* __restrict__ W2,
              const float* __restrict__ b1, float* __restrict__ g) {
    const int lane = threadIdx.x & 63;
    const int wid  = threadIdx.x >> 6;
    const int d    = blockIdx.x * 4 + wid;
    if (d >= N_NODES) return;                  // wave-uniform
    const int j4 = lane & 3, slot = lane >> 2;
    const int start = row_ptr[d];
    const int deg   = deg_in[d];
    const int end   = start + deg;
    f4 agg = 0.f;
    for (int p = start + slot; p < end; p += 16) {
        int s = adj[p];
        agg += ((const f4*)h)[s * 4 + j4];
    }
#pragma unroll
    for (int off = 4; off < 64; off <<= 1) {
        agg[0] += __shfl_xor(agg[0], off);
        agg[1] += __shfl_xor(agg[1], off);
        agg[2] += __shfl_xor(agg[2], off);
        agg[3] += __shfl_xor(agg[3], off);
    }
    __shared__ float st[4][NH];
    const float nd = rsqrtf((float)max(deg, 1));
    if (slot == 0) {
        f4 bb = ((const f4*)b1)[j4];
        f4 tj;
        tj[0] = fmaxf(fmaf(agg[0], nd, bb[0]), 0.f);
        tj[1] = fmaxf(fmaf(agg[1], nd, bb[1]), 0.f);
        tj[2] = fmaxf(fmaf(agg[2], nd, bb[2]), 0.f);
        tj[3] = fmaxf(fmaf(agg[3], nd, bb[3]), 0.f);
        ((f4*)st[wid])[j4] = tj;
    }
    __builtin_amdgcn_wave_barrier();
    float r = 0.f;
    if (lane < NO) {
#pragma unroll
        for (int qq = 0; qq < NH; ++qq)
            r = fmaf(st[wid][qq], W2[qq * NO + lane], r);
    }
    if (lane < 8) {
        float ns = rsqrtf((float)max(deg_out[d], 1));
        g[(size_t)d * 8 + lane] = (lane < NO) ? ns * r : 0.f;  // zero the pad slot
    }
}

// ---------------- K6: gather layer2 -> out ----------------
// one wave per node; 2 lanes x float4 per edge -> 32 edges per wave-iteration
__global__ __launch_bounds__(256)
void k_layer2(const float* __restrict__ g, const int* __restrict__ adj,
              const int* __restrict__ row_ptr, const int* __restrict__ deg_in,
              const float* __restrict__ b2, float* __restrict__ out) {
    const int lane = threadIdx.x & 63;
    const int wid  = threadIdx.x >> 6;
    const int d    = blockIdx.x * 4 + wid;
    if (d >= N_NODES) return;
    const int o4 = lane & 1, slot = lane >> 1;
    const int start = row_ptr[d];
    const int deg   = deg_in[d];
    const int end   = start + deg;
    f4 agg = 0.f;
    for (int p = start + slot; p < end; p += 32) {
        int s = adj[p];
        agg += ((const f4*)g)[s * 2 + o4];
    }
#pragma unroll
    for (int off = 2; off < 64; off <<= 1) {
        agg[0] += __shfl_xor(agg[0], off);
        agg[1] += __shfl_xor(agg[1], off);
        agg[2] += __shfl_xor(agg[2], off);
        agg[3] += __shfl_xor(agg[3], off);
    }
    // every even lane holds o=0..3 sums, every odd lane holds o=4..7 sums
    const int sl = lane >> 2;       // source lane (0 even-class, 1 odd-class)
    float v0 = __shfl(agg[0], sl);
    float v1 = __shfl(agg[1], sl);
    float v2 = __shfl(agg[2], sl);
    float v3 = __shfl(agg[3], sl);
    int cm = lane & 3;
    float v = (cm == 0) ? v0 : (cm == 1) ? v1 : (cm == 2) ? v2 : v3;
    if (lane < NO) {
        float nd = rsqrtf((float)max(deg, 1));
        out[(size_t)d * NO + lane] = fmaf(v, nd, b2[lane]);
    }
}

extern "C" void kernel_launch(void* const* d_in, const int* in_sizes, int n_in,
                              void* d_out, int out_size, void* d_ws, size_t ws_size,
                              hipStream_t stream) {
    const float* X   = (const float*)d_in[0];
    const int*   src = (const int*)d_in[1];
    const int*   dst = (const int*)d_in[2];
    const float* W1  = (const float*)d_in[3];
    const float* b1  = (const float*)d_in[4];
    const float* W2  = (const float*)d_in[5];
    const float* b2  = (const float*)d_in[6];
    float* out = (float*)d_out;

    char* w = (char*)d_ws;
    float* h        = (float*)w;  w += (size_t)N_NODES * NH * 4;   // 6.4 MB
    float* g        = (float*)w;  w += (size_t)N_NODES * 8 * 4;    // 3.2 MB
    int*   adj      = (int*)w;    w += (size_t)N_EDGES * 4;        // 12.8 MB
    int*   deg_out_a= (int*)w;    w += (size_t)N_NODES * 4;
    int*   deg_in_a = (int*)w;    w += (size_t)N_NODES * 4;
    int*   row_ptr  = (int*)w;    w += (size_t)N_NODES * 4;
    int*   cursor   = (int*)w;    w += (size_t)N_NODES * 4;
    int*   bsum     = (int*)w;    w += 512 * 4;
    int*   boff     = (int*)w;    w += 512 * 4;

    hipMemsetAsync(deg_out_a, 0, (size_t)N_NODES * 2 * 4, stream);

    k_degrees<<<1024, 256, 0, stream>>>(src, dst, deg_out_a, deg_in_a);
    k_bsum  <<<NBLK_N, 256, 0, stream>>>(deg_in_a, bsum);
    k_scan  <<<1, 512, 0, stream>>>(bsum, boff);
    k_rowptr<<<NBLK_N, 256, 0, stream>>>(deg_in_a, boff, row_ptr, cursor);
    k_fill  <<<1024, 256, 0, stream>>>(src, dst, cursor, adj);
    k_gemm1 <<<GBLK, 128, 0, stream>>>(X, W1, deg_out_a, h);
    k_layer1<<<(N_NODES + 3) / 4, 256, 0, stream>>>(h, adj, row_ptr, deg_in_a,
                                                    deg_out_a, W2, b1, g);
    k_layer2<<<(N_NODES + 3) / 4, 256, 0, stream>>>(g, adj, row_ptr, deg_in_a,
                                                    b2, out);
}

// Round 3
// 794.970 us; speedup vs baseline: 1.1521x; 1.1521x over previous
//
#include <hip/hip_runtime.h>
#include <math.h>

#define N_NODES  100000
#define N_EDGES  3200000
#define K_IN     1433
#define NH       16
#define NO       7

#define TK       16
#define NC       ((K_IN + TK - 1) / TK)      // 90 chunks
#define KSPLIT   9
#define CPS      10                           // chunks per split (9*10 = 90)
#define LSTR     68                           // transposed-tile row stride (floats)
#define GR       64                           // rows per wave-tile
#define NTILE    ((N_NODES + GR - 1) / GR)    // 1563
#define NWAVE    (NTILE * KSPLIT)             // 14067
#define SLOT     96                           // adjacency slots per node

typedef float f4  __attribute__((ext_vector_type(4)));
typedef float f4u __attribute__((ext_vector_type(4), aligned(4)));

// ---------------- K1: single-pass build (deg_out, deg_in/cursor, slotted adj) ----
__global__ __launch_bounds__(256)
void k_build(const int* __restrict__ src, const int* __restrict__ dst,
             int* __restrict__ deg_out, int* __restrict__ cnt,
             int* __restrict__ adj) {
    int i = blockIdx.x * blockDim.x + threadIdx.x;
    int stride = gridDim.x * blockDim.x;
    for (; i < N_EDGES; i += stride) {
        int s = src[i], d = dst[i];
        atomicAdd(&deg_out[s], 1);
        int p = atomicAdd(&cnt[d], 1);
        if (p < SLOT) adj[d * SLOT + p] = s;
    }
}

// ---------------- K2: hpart[split] = X[:, ksplit] @ W1[ksplit, :] ----------------
// 64-row x 160-k wave-tiles; 4 independent waves/block; no __syncthreads.
__global__ __launch_bounds__(256)
void k_gemm1(const float* __restrict__ X, const float* __restrict__ W1,
             float* __restrict__ hpart) {
    __shared__ float sX[4][TK * LSTR];
    const int wid = threadIdx.x >> 6;
    const int t   = threadIdx.x & 63;
    const int wg  = blockIdx.x * 4 + wid;
    if (wg >= NWAVE) return;                   // wave-uniform
    const int tile  = wg / KSPLIT;
    const int split = wg - tile * KSPLIT;
    const int row_base = tile * GR;
    float* lds = sX[wid];
    const int q = t & 3;          // 16B granule within chunk
    const int rsub = t >> 2;      // 0..15

    int rg[4];
#pragma unroll
    for (int i = 0; i < 4; ++i)
        rg[i] = min(row_base + i * 16 + rsub, N_NODES - 1);

    f4 acc0 = 0.f, acc1 = 0.f, acc2 = 0.f, acc3 = 0.f;
    f4 rv[4];

    const int c0 = split * CPS;
    // prologue: stage chunk c0 (k = c0*16 + 4q <= 1292, always in range)
    {
        const int k = c0 * TK + 4 * q;
#pragma unroll
        for (int i = 0; i < 4; ++i)
            rv[i] = *(const f4u*)(X + (size_t)rg[i] * K_IN + k);
    }

    for (int cc = 0; cc < CPS; ++cc) {
        const int c = c0 + cc;
        const int kcol = 4 * q;
        // regs -> transposed LDS
#pragma unroll
        for (int i = 0; i < 4; ++i) {
            int r = i * 16 + rsub;
            lds[(kcol + 0) * LSTR + r] = rv[i][0];
            lds[(kcol + 1) * LSTR + r] = rv[i][1];
            lds[(kcol + 2) * LSTR + r] = rv[i][2];
            lds[(kcol + 3) * LSTR + r] = rv[i][3];
        }
        // issue next-chunk loads (in flight across compute)
        if (cc + 1 < CPS) {
            const int kn = (c + 1) * TK + 4 * q;
            if (kn + 3 < K_IN) {
#pragma unroll
                for (int i = 0; i < 4; ++i)
                    rv[i] = *(const f4u*)(X + (size_t)rg[i] * K_IN + kn);
            } else {
#pragma unroll
                for (int i = 0; i < 4; ++i) {
                    const float* xr = X + (size_t)rg[i] * K_IN;
#pragma unroll
                    for (int m = 0; m < 4; ++m)
                        rv[i][m] = (kn + m < K_IN) ? xr[kn + m] : 0.f;
                }
            }
        }
        __builtin_amdgcn_wave_barrier();   // LDS writes before reads
        const int k0 = c * TK;
#pragma unroll
        for (int kk = 0; kk < TK; ++kk) {
            float x = lds[kk * LSTR + t];
            int wk = min(k0 + kk, K_IN - 1);        // uniform; tail lanes have x==0
            const float* wr = W1 + wk * NH;
            acc0 += x * *(const f4*)(wr + 0);
            acc1 += x * *(const f4*)(wr + 4);
            acc2 += x * *(const f4*)(wr + 8);
            acc3 += x * *(const f4*)(wr + 12);
        }
        __builtin_amdgcn_wave_barrier();   // next writes after reads
    }

    const int rgo = row_base + t;
    if (rgo < N_NODES) {
        f4* hp = (f4*)(hpart + ((size_t)split * N_NODES + rgo) * NH);
        hp[0] = acc0; hp[1] = acc1; hp[2] = acc2; hp[3] = acc3;
    }
}

// ---------------- K3: h = norm_src * sum_s hpart[s] ----------------
__global__ __launch_bounds__(256)
void k_reduce(const float* __restrict__ hpart, const int* __restrict__ deg_out,
              float* __restrict__ h) {
    int idx = blockIdx.x * 256 + threadIdx.x;   // f4 index
    if (idx >= N_NODES * 4) return;
    f4 a = 0.f;
#pragma unroll
    for (int s = 0; s < KSPLIT; ++s)
        a += ((const f4*)hpart)[(size_t)s * N_NODES * 4 + idx];
    float ns = rsqrtf((float)max(deg_out[idx >> 2], 1));
    ((f4*)h)[idx] = a * ns;
}

// ---------------- K4: gather layer1 + relu + fused (.. @ W2) ----------------
// one wave per node; 4 lanes x float4 per edge -> 16 edges per wave-iteration
__global__ __launch_bounds__(256)
void k_layer1(const float* __restrict__ h, const int* __restrict__ adj,
              const int* __restrict__ cnt, const int* __restrict__ deg_out,
              const float* __restrict__ W2, const float* __restrict__ b1,
              float* __restrict__ g) {
    const int lane = threadIdx.x & 63;
    const int wid  = threadIdx.x >> 6;
    const int d    = blockIdx.x * 4 + wid;
    if (d >= N_NODES) return;                  // wave-uniform
    const int j4 = lane & 3, slot = lane >> 2;
    const int start = d * SLOT;
    const int deg   = min(cnt[d], SLOT);
    const int end   = start + deg;
    f4 agg = 0.f;
    for (int p = start + slot; p < end; p += 16) {
        int s = adj[p];
        agg += ((const f4*)h)[s * 4 + j4];
    }
#pragma unroll
    for (int off = 4; off < 64; off <<= 1) {
        agg[0] += __shfl_xor(agg[0], off);
        agg[1] += __shfl_xor(agg[1], off);
        agg[2] += __shfl_xor(agg[2], off);
        agg[3] += __shfl_xor(agg[3], off);
    }
    __shared__ float st[4][NH];
    const float nd = rsqrtf((float)max(deg, 1));
    if (slot == 0) {
        f4 bb = ((const f4*)b1)[j4];
        f4 tj;
        tj[0] = fmaxf(fmaf(agg[0], nd, bb[0]), 0.f);
        tj[1] = fmaxf(fmaf(agg[1], nd, bb[1]), 0.f);
        tj[2] = fmaxf(fmaf(agg[2], nd, bb[2]), 0.f);
        tj[3] = fmaxf(fmaf(agg[3], nd, bb[3]), 0.f);
        ((f4*)st[wid])[j4] = tj;
    }
    __builtin_amdgcn_wave_barrier();
    float r = 0.f;
    if (lane < NO) {
#pragma unroll
        for (int qq = 0; qq < NH; ++qq)
            r = fmaf(st[wid][qq], W2[qq * NO + lane], r);
    }
    if (lane < 8) {
        float ns = rsqrtf((float)max(deg_out[d], 1));
        g[(size_t)d * 8 + lane] = (lane < NO) ? ns * r : 0.f;  // zero pad slot
    }
}

// ---------------- K5: gather layer2 -> out ----------------
// one wave per node; 2 lanes x float4 per edge -> 32 edges per wave-iteration
__global__ __launch_bounds__(256)
void k_layer2(const float* __restrict__ g, const int* __restrict__ adj,
              const int* __restrict__ cnt, const float* __restrict__ b2,
              float* __restrict__ out) {
    const int lane = threadIdx.x & 63;
    const int wid  = threadIdx.x >> 6;
    const int d    = blockIdx.x * 4 + wid;
    if (d >= N_NODES) return;
    const int o4 = lane & 1, slot = lane >> 1;
    const int start = d * SLOT;
    const int deg   = min(cnt[d], SLOT);
    const int end   = start + deg;
    f4 agg = 0.f;
    for (int p = start + slot; p < end; p += 32) {
        int s = adj[p];
        agg += ((const f4*)g)[s * 2 + o4];
    }
#pragma unroll
    for (int off = 2; off < 64; off <<= 1) {
        agg[0] += __shfl_xor(agg[0], off);
        agg[1] += __shfl_xor(agg[1], off);
        agg[2] += __shfl_xor(agg[2], off);
        agg[3] += __shfl_xor(agg[3], off);
    }
    // even lanes hold o=0..3 sums, odd lanes hold o=4..7 sums
    const int sl = lane >> 2;
    float v0 = __shfl(agg[0], sl);
    float v1 = __shfl(agg[1], sl);
    float v2 = __shfl(agg[2], sl);
    float v3 = __shfl(agg[3], sl);
    int cm = lane & 3;
    float v = (cm == 0) ? v0 : (cm == 1) ? v1 : (cm == 2) ? v2 : v3;
    if (lane < NO) {
        float nd = rsqrtf((float)max(deg, 1));
        out[(size_t)d * NO + lane] = fmaf(v, nd, b2[lane]);
    }
}

extern "C" void kernel_launch(void* const* d_in, const int* in_sizes, int n_in,
                              void* d_out, int out_size, void* d_ws, size_t ws_size,
                              hipStream_t stream) {
    const float* X   = (const float*)d_in[0];
    const int*   src = (const int*)d_in[1];
    const int*   dst = (const int*)d_in[2];
    const float* W1  = (const float*)d_in[3];
    const float* b1  = (const float*)d_in[4];
    const float* W2  = (const float*)d_in[5];
    const float* b2  = (const float*)d_in[6];
    float* out = (float*)d_out;

    char* w = (char*)d_ws;
    float* hpart    = (float*)w;  w += (size_t)KSPLIT * N_NODES * NH * 4; // 57.6 MB
    float* h        = (float*)w;  w += (size_t)N_NODES * NH * 4;          // 6.4 MB
    float* g        = (float*)w;  w += (size_t)N_NODES * 8 * 4;           // 3.2 MB
    int*   adj      = (int*)w;    w += (size_t)N_NODES * SLOT * 4;        // 38.4 MB
    int*   deg_out_a= (int*)w;    w += (size_t)N_NODES * 4;
    int*   cnt      = (int*)w;    w += (size_t)N_NODES * 4;

    // deg_out_a and cnt are contiguous: one memset
    hipMemsetAsync(deg_out_a, 0, (size_t)N_NODES * 2 * 4, stream);

    k_build <<<2048, 256, 0, stream>>>(src, dst, deg_out_a, cnt, adj);
    k_gemm1 <<<(NWAVE + 3) / 4, 256, 0, stream>>>(X, W1, hpart);
    k_reduce<<<(N_NODES * 4 + 255) / 256, 256, 0, stream>>>(hpart, deg_out_a, h);
    k_layer1<<<(N_NODES + 3) / 4, 256, 0, stream>>>(h, adj, cnt, deg_out_a,
                                                    W2, b1, g);
    k_layer2<<<(N_NODES + 3) / 4, 256, 0, stream>>>(g, adj, cnt, b2, out);
}

// Round 5
// 589.381 us; speedup vs baseline: 1.5540x; 1.3488x over previous
//
#include <hip/hip_runtime.h>
#include <math.h>

#define N_NODES  100000
#define N_EDGES  3200000
#define K_IN     1433
#define NH       16
#define NO       7

#define TK       16
#define KSPLIT   9
#define CPS      10                           // chunks per split (9*10*16 = 1440 >= 1433)
#define RW       (CPS * TK)                   // 160 W1 rows per split
#define LSTR     68                           // transposed X-tile row stride (floats)
#define GR       64                           // rows per wave-tile
#define NTILE    ((N_NODES + GR - 1) / GR)    // 1563
#define NRB      ((NTILE + 3) / 4)            // 391 row-blocks (4 tiles/block)
#define SLOT     96                           // adjacency slots per node

typedef float f4  __attribute__((ext_vector_type(4)));
typedef float f4u __attribute__((ext_vector_type(4), aligned(4)));

// ---------------- K1: single-pass build (deg_out, deg_in/cursor, slotted adj) ----
__global__ __launch_bounds__(256)
void k_build(const int* __restrict__ src, const int* __restrict__ dst,
             int* __restrict__ deg_out, int* __restrict__ cnt,
             int* __restrict__ adj) {
    int i = blockIdx.x * blockDim.x + threadIdx.x;
    int stride = gridDim.x * blockDim.x;
    for (; i < N_EDGES; i += stride) {
        int s = src[i], d = dst[i];
        atomicAdd(&deg_out[s], 1);
        int p = atomicAdd(&cnt[d], 1);
        if (p < SLOT) adj[d * SLOT + p] = s;
    }
}

// ---------------- K2: hpart[split] = X[:, ksplit] @ W1[ksplit, :] ----------------
// Block = 4 row-tiles (one per wave) x ONE k-split. W1 slice staged in LDS once;
// inner loop reads W1 as wave-uniform ds_read_b128 broadcasts (no s_loads, no
// scalar-cache misses on the critical path). X staged via transposed LDS tile.
__global__ __launch_bounds__(256)
void k_gemm1(const float* __restrict__ X, const float* __restrict__ W1,
             float* __restrict__ hpart) {
    __shared__ float wlds[RW * NH];            // 10240 B = 640 f4
    __shared__ float sX[4][TK * LSTR];         // 17408 B
    const int wid = threadIdx.x >> 6;
    const int t   = threadIdx.x & 63;
    const int rb    = blockIdx.x % NRB;
    const int split = blockIdx.x / NRB;

    // ---- stage this split's W1 slice into LDS (zero-fill past K_IN) ----
    {
        const f4* W1v = (const f4*)W1;         // each W1 row = 4 f4
        const int base = split * RW;
#pragma unroll
        for (int r = 0; r < 3; ++r) {          // ceil(640/256) = 3 iters
            int idx  = r * 256 + threadIdx.x;  // f4 index into wlds
            if (idx < RW * 4) {
                int krow = base + (idx >> 2);
                f4 wv = 0.f;
                if (krow < K_IN) wv = W1v[krow * 4 + (idx & 3)];
                ((f4*)wlds)[idx] = wv;
            }
        }
    }
    __syncthreads();

    const int tile = rb * 4 + wid;
    if (tile >= NTILE) return;                 // wave-uniform, after the sync
    const int row_base = tile * GR;
    float* lds = sX[wid];
    const int q = t & 3;          // 16B granule within chunk
    const int rsub = t >> 2;      // 0..15

    int rg[4];
#pragma unroll
    for (int i = 0; i < 4; ++i)
        rg[i] = min(row_base + i * 16 + rsub, N_NODES - 1);

    f4 acc0 = 0.f, acc1 = 0.f, acc2 = 0.f, acc3 = 0.f;
    f4 rv[4];

    const int c0 = split * CPS;
    // prologue: stage chunk c0 (k = c0*16 + 4q <= 1295, always in range)
    {
        const int k = c0 * TK + 4 * q;
#pragma unroll
        for (int i = 0; i < 4; ++i)
            rv[i] = *(const f4u*)(X + (size_t)rg[i] * K_IN + k);
    }

    for (int cc = 0; cc < CPS; ++cc) {
        const int kcol = 4 * q;
        // regs -> transposed LDS
#pragma unroll
        for (int i = 0; i < 4; ++i) {
            int r = i * 16 + rsub;
            lds[(kcol + 0) * LSTR + r] = rv[i][0];
            lds[(kcol + 1) * LSTR + r] = rv[i][1];
            lds[(kcol + 2) * LSTR + r] = rv[i][2];
            lds[(kcol + 3) * LSTR + r] = rv[i][3];
        }
        // issue next-chunk loads (in flight across compute)
        if (cc + 1 < CPS) {
            const int kn = (c0 + cc + 1) * TK + 4 * q;
            if (kn + 3 < K_IN) {
#pragma unroll
                for (int i = 0; i < 4; ++i)
                    rv[i] = *(const f4u*)(X + (size_t)rg[i] * K_IN + kn);
            } else {
#pragma unroll
                for (int i = 0; i < 4; ++i) {
                    const float* xr = X + (size_t)rg[i] * K_IN;
#pragma unroll
                    for (int m = 0; m < 4; ++m)
                        rv[i][m] = (kn + m < K_IN) ? xr[kn + m] : 0.f;
                }
            }
        }
        __builtin_amdgcn_wave_barrier();   // LDS writes before reads
#pragma unroll
        for (int kk = 0; kk < TK; ++kk) {
            float x = lds[kk * LSTR + t];
            const f4* wr = (const f4*)(wlds + (cc * TK + kk) * NH);  // uniform -> broadcast
            acc0 += x * wr[0];
            acc1 += x * wr[1];
            acc2 += x * wr[2];
            acc3 += x * wr[3];
        }
        __builtin_amdgcn_wave_barrier();   // next writes after reads
    }

    const int rgo = row_base + t;
    if (rgo < N_NODES) {
        f4* hp = (f4*)(hpart + ((size_t)split * N_NODES + rgo) * NH);
        hp[0] = acc0; hp[1] = acc1; hp[2] = acc2; hp[3] = acc3;
    }
}

// ---------------- K3: h = norm_src * sum_s hpart[s] ----------------
__global__ __launch_bounds__(256)
void k_reduce(const float* __restrict__ hpart, const int* __restrict__ deg_out,
              float* __restrict__ h) {
    int idx = blockIdx.x * 256 + threadIdx.x;   // f4 index
    if (idx >= N_NODES * 4) return;
    f4 a = 0.f;
#pragma unroll
    for (int s = 0; s < KSPLIT; ++s)
        a += ((const f4*)hpart)[(size_t)s * N_NODES * 4 + idx];
    float ns = rsqrtf((float)max(deg_out[idx >> 2], 1));
    ((f4*)h)[idx] = a * ns;
}

// ---------------- K4: gather layer1 + relu + fused (.. @ W2) ----------------
__global__ __launch_bounds__(256)
void k_layer1(const float* __restrict__ h, const int* __restrict__ adj,
              const int* __restrict__ cnt, const int* __restrict__ deg_out,
              const float* __restrict__ W2, const float* __restrict__ b1,
              float* __restrict__ g) {
    const int lane = threadIdx.x & 63;
    const int wid  = threadIdx.x >> 6;
    const int d    = blockIdx.x * 4 + wid;
    if (d >= N_NODES) return;                  // wave-uniform
    const int j4 = lane & 3, slot = lane >> 2;
    const int start = d * SLOT;
    const int deg   = min(cnt[d], SLOT);
    const int end   = start + deg;
    f4 agg = 0.f;
    for (int p = start + slot; p < end; p += 16) {
        int s = adj[p];
        agg += ((const f4*)h)[s * 4 + j4];
    }
#pragma unroll
    for (int off = 4; off < 64; off <<= 1) {
        agg[0] += __shfl_xor(agg[0], off);
        agg[1] += __shfl_xor(agg[1], off);
        agg[2] += __shfl_xor(agg[2], off);
        agg[3] += __shfl_xor(agg[3], off);
    }
    __shared__ float st[4][NH];
    const float nd = rsqrtf((float)max(deg, 1));
    if (slot == 0) {
        f4 bb = ((const f4*)b1)[j4];
        f4 tj;
        tj[0] = fmaxf(fmaf(agg[0], nd, bb[0]), 0.f);
        tj[1] = fmaxf(fmaf(agg[1], nd, bb[1]), 0.f);
        tj[2] = fmaxf(fmaf(agg[2], nd, bb[2]), 0.f);
        tj[3] = fmaxf(fmaf(agg[3], nd, bb[3]), 0.f);
        ((f4*)st[wid])[j4] = tj;
    }
    __builtin_amdgcn_wave_barrier();
    float r = 0.f;
    if (lane < NO) {
#pragma unroll
        for (int qq = 0; qq < NH; ++qq)
            r = fmaf(st[wid][qq], W2[qq * NO + lane], r);
    }
    if (lane < 8) {
        float ns = rsqrtf((float)max(deg_out[d], 1));
        g[(size_t)d * 8 + lane] = (lane < NO) ? ns * r : 0.f;  // zero pad slot
    }
}

// ---------------- K5: gather layer2 -> out ----------------
__global__ __launch_bounds__(256)
void k_layer2(const float* __restrict__ g, const int* __restrict__ adj,
              const int* __restrict__ cnt, const float* __restrict__ b2,
              float* __restrict__ out) {
    const int lane = threadIdx.x & 63;
    const int wid  = threadIdx.x >> 6;
    const int d    = blockIdx.x * 4 + wid;
    if (d >= N_NODES) return;
    const int o4 = lane & 1, slot = lane >> 1;
    const int start = d * SLOT;
    const int deg   = min(cnt[d], SLOT);
    const int end   = start + deg;
    f4 agg = 0.f;
    for (int p = start + slot; p < end; p += 32) {
        int s = adj[p];
        agg += ((const f4*)g)[s * 2 + o4];
    }
#pragma unroll
    for (int off = 2; off < 64; off <<= 1) {
        agg[0] += __shfl_xor(agg[0], off);
        agg[1] += __shfl_xor(agg[1], off);
        agg[2] += __shfl_xor(agg[2], off);
        agg[3] += __shfl_xor(agg[3], off);
    }
    // even lanes hold o=0..3 sums, odd lanes hold o=4..7 sums
    const int sl = lane >> 2;
    float v0 = __shfl(agg[0], sl);
    float v1 = __shfl(agg[1], sl);
    float v2 = __shfl(agg[2], sl);
    float v3 = __shfl(agg[3], sl);
    int cm = lane & 3;
    float v = (cm == 0) ? v0 : (cm == 1) ? v1 : (cm == 2) ? v2 : v3;
    if (lane < NO) {
        float nd = rsqrtf((float)max(deg, 1));
        out[(size_t)d * NO + lane] = fmaf(v, nd, b2[lane]);
    }
}

extern "C" void kernel_launch(void* const* d_in, const int* in_sizes, int n_in,
                              void* d_out, int out_size, void* d_ws, size_t ws_size,
                              hipStream_t stream) {
    const float* X   = (const float*)d_in[0];
    const int*   src = (const int*)d_in[1];
    const int*   dst = (const int*)d_in[2];
    const float* W1  = (const float*)d_in[3];
    const float* b1  = (const float*)d_in[4];
    const float* W2  = (const float*)d_in[5];
    const float* b2  = (const float*)d_in[6];
    float* out = (float*)d_out;

    char* w = (char*)d_ws;
    float* hpart    = (float*)w;  w += (size_t)KSPLIT * N_NODES * NH * 4; // 57.6 MB
    float* h        = (float*)w;  w += (size_t)N_NODES * NH * 4;          // 6.4 MB
    float* g        = (float*)w;  w += (size_t)N_NODES * 8 * 4;           // 3.2 MB
    int*   adj      = (int*)w;    w += (size_t)N_NODES * SLOT * 4;        // 38.4 MB
    int*   deg_out_a= (int*)w;    w += (size_t)N_NODES * 4;
    int*   cnt      = (int*)w;    w += (size_t)N_NODES * 4;

    hipMemsetAsync(deg_out_a, 0, (size_t)N_NODES * 2 * 4, stream);

    k_build <<<2048, 256, 0, stream>>>(src, dst, deg_out_a, cnt, adj);
    k_gemm1 <<<NRB * KSPLIT, 256, 0, stream>>>(X, W1, hpart);
    k_reduce<<<(N_NODES * 4 + 255) / 256, 256, 0, stream>>>(hpart, deg_out_a, h);
    k_layer1<<<(N_NODES + 3) / 4, 256, 0, stream>>>(h, adj, cnt, deg_out_a,
                                                    W2, b1, g);
    k_layer2<<<(N_NODES + 3) / 4, 256, 0, stream>>>(g, adj, cnt, b2, out);
}